// Round 1
// baseline (3167.971 us; speedup 1.0000x reference)
//
#include <hip/hip_runtime.h>
#include <cstdint>
#include <cstddef>

#define TOKENS 8192
#define HD 2048
#define FD 5632
#define NE 8
#define BM 256
#define BN 128
#define BK 32
#define MAXMT 72
#define NSLOTS (MAXMT * BM) /* 18432 */
#define LDA 40              /* LDS row stride in ushorts (32 + 8 pad, keeps 16B align) */

typedef __attribute__((ext_vector_type(8))) short short8;
typedef __attribute__((ext_vector_type(4))) float floatx4;

// ---------------- workspace layout (bytes) ----------------
#define OFF_CNT 0ULL           /* 8 ints  */
#define OFF_CNT2 32ULL         /* 8 ints  */
#define OFF_OFFS 64ULL         /* 9 ints  */
#define OFF_TILE_E 128ULL      /* 72 ints */
#define OFF_TILE_MB 416ULL     /* 72 ints */
#define OFF_TOTAL 704ULL       /* 1 int   */
#define OFF_TOPE 768ULL        /* 16384 ints  -> 66304 */
#define OFF_TOPW 66304ULL      /* 16384 f32   -> 131840 */
#define OFF_STOK 131840ULL     /* 18432 ints  -> 205568 */
#define OFF_SW 205568ULL       /* 18432 f32   -> 279296 */
#define OFF_XG 279552ULL       /* 18432*2048*2 -> 75777024 */
#define OFF_ACT 75777024ULL    /* 18432*5632*2 -> 283395072 */
#define OFF_WB 283395072ULL    /* 3*92274688*2 -> 837043200 */
#define NEED_BASE 283395072ULL
#define NEED_WB 837043200ULL
#define EFH 92274688ULL /* 8*5632*2048 */

__device__ __forceinline__ unsigned short f2bf(float f) {
  unsigned int u = __float_as_uint(f);
  unsigned int r = u + 0x7fffu + ((u >> 16) & 1u);
  return (unsigned short)(r >> 16);
}

union U8 { unsigned short s[8]; uint4 q; };
union U4 { unsigned short s[4]; uint2 q; };

// ---------------- weight f32 -> bf16 conversion ----------------
__global__ void cvt_bf16_kernel(const float* __restrict__ src, unsigned short* __restrict__ dst) {
  size_t i = ((size_t)blockIdx.x * 256 + threadIdx.x) * 4;
  float4 v = *(const float4*)(src + i);
  U4 t;
  t.s[0] = f2bf(v.x); t.s[1] = f2bf(v.y); t.s[2] = f2bf(v.z); t.s[3] = f2bf(v.w);
  *(uint2*)(dst + i) = t.q;
}

// ---------------- router: logits + top2 + counts ----------------
__global__ void router_kernel(const float* __restrict__ x, const float* __restrict__ rW,
                              const int* __restrict__ limit_p, float* __restrict__ logits,
                              int* __restrict__ top_e, float* __restrict__ top_w,
                              int* __restrict__ cnt) {
  const int wid = threadIdx.x >> 6, lane = threadIdx.x & 63;
  const int t = blockIdx.x * 4 + wid;
  const float* xr = x + (size_t)t * HD;
  float acc[NE];
#pragma unroll
  for (int e = 0; e < NE; ++e) acc[e] = 0.f;
#pragma unroll
  for (int c = 0; c < 8; ++c) {
    const int col = c * 256 + lane * 4;
    float4 xv = *(const float4*)(xr + col);
#pragma unroll
    for (int e = 0; e < NE; ++e) {
      float4 wv = *(const float4*)(rW + e * HD + col);
      acc[e] += xv.x * wv.x + xv.y * wv.y + xv.z * wv.z + xv.w * wv.w;
    }
  }
#pragma unroll
  for (int e = 0; e < NE; ++e) {
#pragma unroll
    for (int off = 32; off; off >>= 1) acc[e] += __shfl_xor(acc[e], off, 64);
  }
  if (lane == 0) {
    const int limit = *limit_p;
    const float ninf = -__builtin_huge_valf();
    float v[NE];
#pragma unroll
    for (int e = 0; e < NE; ++e) {
      v[e] = (e < limit) ? acc[e] : ninf;
      logits[(size_t)t * NE + e] = v[e];
    }
    int e0 = 0; float v0 = v[0];
#pragma unroll
    for (int e = 1; e < NE; ++e) if (v[e] > v0) { v0 = v[e]; e0 = e; }
    int e1 = -1; float v1 = ninf;
#pragma unroll
    for (int e = 0; e < NE; ++e) if (e != e0 && v[e] > v1) { v1 = v[e]; e1 = e; }
    float z = __expf(v1 - v0);
    float w0 = 1.f / (1.f + z);
    float w1 = z * w0;
    top_e[t * 2] = e0; top_w[t * 2] = w0;
    top_e[t * 2 + 1] = e1; top_w[t * 2 + 1] = w1;
    atomicAdd(&cnt[e0], 1);
    atomicAdd(&cnt[e1], 1);
  }
}

// ---------------- offsets + tile table ----------------
__global__ void offsets_kernel(const int* __restrict__ cnt, int* __restrict__ offs,
                               int* __restrict__ tile_e, int* __restrict__ tile_mb,
                               int* __restrict__ total) {
  if (threadIdx.x == 0) {
    int off = 0, tt = 0;
    for (int e = 0; e < NE; ++e) {
      int c = cnt[e];
      int tiles = (c + BM - 1) / BM;
      for (int i = 0; i < tiles; ++i) { tile_e[tt] = e; tile_mb[tt] = off + i * BM; ++tt; }
      offs[e] = off;
      off += tiles * BM;
    }
    offs[NE] = off;
    *total = tt;
  }
}

// ---------------- assignment -> slots ----------------
__global__ void assign_kernel(const int* __restrict__ top_e, const float* __restrict__ top_w,
                              const int* __restrict__ offs, int* __restrict__ cnt2,
                              int* __restrict__ stok, float* __restrict__ sw) {
  int i = blockIdx.x * 256 + threadIdx.x;
  if (i < TOKENS * 2) {
    int e = top_e[i];
    int pos = atomicAdd(&cnt2[e], 1);
    int slot = offs[e] + pos;
    stok[slot] = i >> 1;
    sw[slot] = top_w[i];
  }
}

// ---------------- gather routed rows -> bf16 ----------------
__global__ void gather_kernel(const float* __restrict__ x, const int* __restrict__ stok,
                              unsigned short* __restrict__ Xg) {
  const int row = blockIdx.x;
  const int tok = stok[row];
  const int c = threadIdx.x * 8;
  U8 t;
  if (tok >= 0) {
    const float* src = x + (size_t)tok * HD + c;
    float4 a = *(const float4*)src;
    float4 b = *(const float4*)(src + 4);
    t.s[0] = f2bf(a.x); t.s[1] = f2bf(a.y); t.s[2] = f2bf(a.z); t.s[3] = f2bf(a.w);
    t.s[4] = f2bf(b.x); t.s[5] = f2bf(b.y); t.s[6] = f2bf(b.z); t.s[7] = f2bf(b.w);
  } else {
    t.q.x = 0; t.q.y = 0; t.q.z = 0; t.q.w = 0;
  }
  *(uint4*)(Xg + (size_t)row * HD + c) = t.q;
}

// ---------------- out = residual ----------------
__global__ void init_out_kernel(const float* __restrict__ r, float* __restrict__ o) {
  size_t i = ((size_t)blockIdx.x * 256 + threadIdx.x) * 4;
  *(float4*)(o + i) = *(const float4*)(r + i);
}

// ---------------- GEMM1: act = silu(Xg @ gW^T) * (Xg @ uW^T) ----------------
template <bool WB>
__global__ __launch_bounds__(512, 1) void gemm1_kernel(
    const unsigned short* __restrict__ Xg, const float* __restrict__ gWf,
    const float* __restrict__ uWf, const unsigned short* __restrict__ gWb,
    const unsigned short* __restrict__ uWb, unsigned short* __restrict__ act,
    const int* __restrict__ tile_e, const int* __restrict__ tile_mb,
    const int* __restrict__ total) {
  const int mt = blockIdx.y;
  if (mt >= *total) return;
  __shared__ __align__(16) unsigned short As[BM * LDA];
  __shared__ __align__(16) unsigned short Gs[BN * LDA];
  __shared__ __align__(16) unsigned short Us[BN * LDA];
  const int e = tile_e[mt];
  const int mbase = tile_mb[mt];
  const int n0 = blockIdx.x * BN;
  const int tid = threadIdx.x;
  const int lane = tid & 63;
  const int wid = tid >> 6;
  const int wm = wid >> 1; /* 0..3 */
  const int wn = wid & 1;  /* 0..1 */
  const int lrow = lane & 15;
  const int lq = lane >> 4;

  const int ar = tid >> 1, ah = tid & 1;
  const int br = tid >> 2, bq = tid & 3;
  const unsigned short* xsrc = Xg + (size_t)(mbase + ar) * HD + ah * 16;
  const size_t brow = ((size_t)e * FD + n0 + br) * HD + bq * 8;
  const float* gsrcf = WB ? nullptr : (gWf + brow);
  const float* usrcf = WB ? nullptr : (uWf + brow);
  const unsigned short* gsrcb = WB ? (gWb + brow) : nullptr;
  const unsigned short* usrcb = WB ? (uWb + brow) : nullptr;

  floatx4 accg[4][4], accu[4][4];
#pragma unroll
  for (int i = 0; i < 4; ++i)
#pragma unroll
    for (int j = 0; j < 4; ++j) {
      accg[i][j] = (floatx4)(0.f);
      accu[i][j] = (floatx4)(0.f);
    }

  for (int kk = 0; kk < HD / BK; ++kk) {
    const int k0 = kk * BK;
    uint4 a0 = *(const uint4*)(xsrc + k0);
    uint4 a1 = *(const uint4*)(xsrc + k0 + 8);
    uint4 gq, uq;
    if constexpr (WB) {
      gq = *(const uint4*)(gsrcb + k0);
      uq = *(const uint4*)(usrcb + k0);
    } else {
      float4 g0 = *(const float4*)(gsrcf + k0);
      float4 g1 = *(const float4*)(gsrcf + k0 + 4);
      float4 u0 = *(const float4*)(usrcf + k0);
      float4 u1 = *(const float4*)(usrcf + k0 + 4);
      U8 tg, tu;
      tg.s[0] = f2bf(g0.x); tg.s[1] = f2bf(g0.y); tg.s[2] = f2bf(g0.z); tg.s[3] = f2bf(g0.w);
      tg.s[4] = f2bf(g1.x); tg.s[5] = f2bf(g1.y); tg.s[6] = f2bf(g1.z); tg.s[7] = f2bf(g1.w);
      tu.s[0] = f2bf(u0.x); tu.s[1] = f2bf(u0.y); tu.s[2] = f2bf(u0.z); tu.s[3] = f2bf(u0.w);
      tu.s[4] = f2bf(u1.x); tu.s[5] = f2bf(u1.y); tu.s[6] = f2bf(u1.z); tu.s[7] = f2bf(u1.w);
      gq = tg.q; uq = tu.q;
    }
    __syncthreads();
    *(uint4*)&As[ar * LDA + ah * 16] = a0;
    *(uint4*)&As[ar * LDA + ah * 16 + 8] = a1;
    *(uint4*)&Gs[br * LDA + bq * 8] = gq;
    *(uint4*)&Us[br * LDA + bq * 8] = uq;
    __syncthreads();
    short8 af[4], gf[4], uf[4];
#pragma unroll
    for (int i = 0; i < 4; ++i)
      af[i] = *(const short8*)&As[(wm * 64 + i * 16 + lrow) * LDA + lq * 8];
#pragma unroll
    for (int j = 0; j < 4; ++j) {
      gf[j] = *(const short8*)&Gs[(wn * 64 + j * 16 + lrow) * LDA + lq * 8];
      uf[j] = *(const short8*)&Us[(wn * 64 + j * 16 + lrow) * LDA + lq * 8];
    }
#pragma unroll
    for (int i = 0; i < 4; ++i)
#pragma unroll
      for (int j = 0; j < 4; ++j) {
        accg[i][j] = __builtin_amdgcn_mfma_f32_16x16x32_bf16(af[i], gf[j], accg[i][j], 0, 0, 0);
        accu[i][j] = __builtin_amdgcn_mfma_f32_16x16x32_bf16(af[i], uf[j], accu[i][j], 0, 0, 0);
      }
  }
#pragma unroll
  for (int i = 0; i < 4; ++i)
#pragma unroll
    for (int j = 0; j < 4; ++j)
#pragma unroll
      for (int r = 0; r < 4; ++r) {
        int m = wm * 64 + i * 16 + lq * 4 + r;
        int n = wn * 64 + j * 16 + lrow;
        float g = accg[i][j][r];
        float u = accu[i][j][r];
        float s = g / (1.f + __expf(-g));
        act[(size_t)(mbase + m) * FD + n0 + n] = f2bf(s * u);
      }
}

// ---------------- GEMM2: out[tok] += w * (act @ dW^T + b) ----------------
template <bool WB>
__global__ __launch_bounds__(512, 2) void gemm2_kernel(
    const unsigned short* __restrict__ act, const float* __restrict__ dWf,
    const unsigned short* __restrict__ dWb, const float* __restrict__ db,
    const int* __restrict__ stok, const float* __restrict__ sw, float* __restrict__ out,
    const int* __restrict__ tile_e, const int* __restrict__ tile_mb,
    const int* __restrict__ total) {
  const int mt = blockIdx.y;
  if (mt >= *total) return;
  __shared__ __align__(16) unsigned short As[BM * LDA];
  __shared__ __align__(16) unsigned short Bs[BN * LDA];
  __shared__ int toksL[BM];
  __shared__ float wLs[BM];
  const int e = tile_e[mt];
  const int mbase = tile_mb[mt];
  const int n0 = blockIdx.x * BN;
  const int tid = threadIdx.x;
  const int lane = tid & 63;
  const int wid = tid >> 6;
  const int wm = wid >> 1;
  const int wn = wid & 1;
  const int lrow = lane & 15;
  const int lq = lane >> 4;

  if (tid < BM) {
    toksL[tid] = stok[mbase + tid];
    wLs[tid] = sw[mbase + tid];
  }

  const int ar = tid >> 1, ah = tid & 1;
  const int br = tid >> 2, bq = tid & 3;
  const unsigned short* asrc = act + (size_t)(mbase + ar) * FD + ah * 16;
  const size_t brow = ((size_t)e * HD + n0 + br) * FD + bq * 8;
  const float* dsrcf = WB ? nullptr : (dWf + brow);
  const unsigned short* dsrcb = WB ? (dWb + brow) : nullptr;

  floatx4 acc[4][4];
#pragma unroll
  for (int i = 0; i < 4; ++i)
#pragma unroll
    for (int j = 0; j < 4; ++j) acc[i][j] = (floatx4)(0.f);

  for (int kk = 0; kk < FD / BK; ++kk) {
    const int k0 = kk * BK;
    uint4 a0 = *(const uint4*)(asrc + k0);
    uint4 a1 = *(const uint4*)(asrc + k0 + 8);
    uint4 dq;
    if constexpr (WB) {
      dq = *(const uint4*)(dsrcb + k0);
    } else {
      float4 d0 = *(const float4*)(dsrcf + k0);
      float4 d1 = *(const float4*)(dsrcf + k0 + 4);
      U8 td;
      td.s[0] = f2bf(d0.x); td.s[1] = f2bf(d0.y); td.s[2] = f2bf(d0.z); td.s[3] = f2bf(d0.w);
      td.s[4] = f2bf(d1.x); td.s[5] = f2bf(d1.y); td.s[6] = f2bf(d1.z); td.s[7] = f2bf(d1.w);
      dq = td.q;
    }
    __syncthreads();
    *(uint4*)&As[ar * LDA + ah * 16] = a0;
    *(uint4*)&As[ar * LDA + ah * 16 + 8] = a1;
    *(uint4*)&Bs[br * LDA + bq * 8] = dq;
    __syncthreads();
    short8 af[4], bf[4];
#pragma unroll
    for (int i = 0; i < 4; ++i)
      af[i] = *(const short8*)&As[(wm * 64 + i * 16 + lrow) * LDA + lq * 8];
#pragma unroll
    for (int j = 0; j < 4; ++j)
      bf[j] = *(const short8*)&Bs[(wn * 64 + j * 16 + lrow) * LDA + lq * 8];
#pragma unroll
    for (int i = 0; i < 4; ++i)
#pragma unroll
      for (int j = 0; j < 4; ++j)
        acc[i][j] = __builtin_amdgcn_mfma_f32_16x16x32_bf16(af[i], bf[j], acc[i][j], 0, 0, 0);
  }
#pragma unroll
  for (int i = 0; i < 4; ++i)
#pragma unroll
    for (int j = 0; j < 4; ++j)
#pragma unroll
      for (int r = 0; r < 4; ++r) {
        int m = wm * 64 + i * 16 + lq * 4 + r;
        int n = wn * 64 + j * 16 + lrow;
        int tok = toksL[m];
        if (tok >= 0) {
          float val = acc[i][j][r] + db[(size_t)e * HD + n0 + n];
          atomicAdd(out + (size_t)tok * HD + n0 + n, wLs[m] * val);
        }
      }
}

extern "C" void kernel_launch(void* const* d_in, const int* in_sizes, int n_in, void* d_out,
                              int out_size, void* d_ws, size_t ws_size, hipStream_t stream) {
  const float* x = (const float*)d_in[0];
  const float* resid = (const float*)d_in[1];
  const float* rW = (const float*)d_in[2];
  const float* gW = (const float*)d_in[3];
  const float* uW = (const float*)d_in[4];
  const float* dW = (const float*)d_in[5];
  const float* db = (const float*)d_in[6];
  const int* lim = (const int*)d_in[7];
  float* out = (float*)d_out;
  float* logits = out + (size_t)TOKENS * HD;

  char* ws = (char*)d_ws;
  int* cnt = (int*)(ws + OFF_CNT);
  int* cnt2 = (int*)(ws + OFF_CNT2);
  int* offs = (int*)(ws + OFF_OFFS);
  int* tile_e = (int*)(ws + OFF_TILE_E);
  int* tile_mb = (int*)(ws + OFF_TILE_MB);
  int* total = (int*)(ws + OFF_TOTAL);
  int* top_e = (int*)(ws + OFF_TOPE);
  float* top_w = (float*)(ws + OFF_TOPW);
  int* stok = (int*)(ws + OFF_STOK);
  float* sw = (float*)(ws + OFF_SW);
  unsigned short* Xg = (unsigned short*)(ws + OFF_XG);
  unsigned short* act = (unsigned short*)(ws + OFF_ACT);
  unsigned short* wb = (unsigned short*)(ws + OFF_WB);
  unsigned short* gWb = wb;
  unsigned short* uWb = wb + EFH;
  unsigned short* dWb = wb + 2 * EFH;

  if (ws_size < NEED_BASE) return; /* cannot run; fail loudly via wrong output */
  const bool use_wb = ws_size >= NEED_WB;

  hipMemsetAsync(ws + OFF_CNT, 0, 64, stream);
  hipMemsetAsync(ws + OFF_STOK, 0xFF, (size_t)NSLOTS * 4, stream);

  if (use_wb) {
    cvt_bf16_kernel<<<90112, 256, 0, stream>>>(gW, gWb);
    cvt_bf16_kernel<<<90112, 256, 0, stream>>>(uW, uWb);
    cvt_bf16_kernel<<<90112, 256, 0, stream>>>(dW, dWb);
  }
  router_kernel<<<TOKENS / 4, 256, 0, stream>>>(x, rW, lim, logits, top_e, top_w, cnt);
  offsets_kernel<<<1, 64, 0, stream>>>(cnt, offs, tile_e, tile_mb, total);
  assign_kernel<<<(TOKENS * 2) / 256, 256, 0, stream>>>(top_e, top_w, offs, cnt2, stok, sw);
  gather_kernel<<<NSLOTS, 256, 0, stream>>>(x, stok, Xg);
  init_out_kernel<<<16384, 256, 0, stream>>>(resid, out);
  if (use_wb) {
    gemm1_kernel<true><<<dim3(FD / BN, MAXMT), 512, 0, stream>>>(Xg, nullptr, nullptr, gWb, uWb,
                                                                 act, tile_e, tile_mb, total);
    gemm2_kernel<true><<<dim3(HD / BN, MAXMT), 512, 0, stream>>>(act, nullptr, dWb, db, stok, sw,
                                                                 out, tile_e, tile_mb, total);
  } else {
    gemm1_kernel<false><<<dim3(FD / BN, MAXMT), 512, 0, stream>>>(Xg, gW, uW, nullptr, nullptr,
                                                                  act, tile_e, tile_mb, total);
    gemm2_kernel<false><<<dim3(HD / BN, MAXMT), 512, 0, stream>>>(act, dW, nullptr, db, stok, sw,
                                                                  out, tile_e, tile_mb, total);
  }
}